// Round 4
// baseline (670.165 us; speedup 1.0000x reference)
//
#include <hip/hip_runtime.h>

typedef unsigned int u32;
typedef unsigned short u16;
typedef __bf16 bf16x8 __attribute__((ext_vector_type(8)));
typedef float f32x4 __attribute__((ext_vector_type(4)));
typedef float f32x16 __attribute__((ext_vector_type(16)));

#define N_SRC 200000
#define N_CTR 100000
#define N_EDGE 800000
#define NBLK 3136  // >= sum_t ceil(cnt_t/64) <= 3133

__device__ __forceinline__ float lo16(u32 u) { return __uint_as_float(u << 16); }
__device__ __forceinline__ float hi16(u32 u) { return __uint_as_float(u & 0xFFFF0000u); }
__device__ __forceinline__ u16 f2b(float f) {
    u32 u = __float_as_uint(f);
    u32 r = (u + 0x7FFFu + ((u >> 16) & 1u)) >> 16;
    return (u16)r;
}

// ---------------------------------------------------------------- dst fill
__global__ __launch_bounds__(256) void dstfill_kernel(const int* __restrict__ ptr,
                                                      int* __restrict__ dst) {
    int c = blockIdx.x * 256 + threadIdx.x;
    if (c < N_CTR) {
        int e1 = ptr[c + 1];
        for (int e = ptr[c]; e < e1; ++e) dst[e] = c;
    }
}

// ---------------------------------------------------- grouping machinery
__global__ __launch_bounds__(256) void fillzero_kernel(int* __restrict__ order,
                                                       int* __restrict__ meta) {
    int i = blockIdx.x * 256 + threadIdx.x;
    if (i < NBLK * 64) order[i] = -1;
    if (blockIdx.x == 0 && threadIdx.x < 16) meta[threadIdx.x] = 0;
}

__global__ __launch_bounds__(256) void hist_kernel(const int* __restrict__ ntype,
                                                   int* __restrict__ meta) {
    __shared__ int lc[8];
    if (threadIdx.x < 8) lc[threadIdx.x] = 0;
    __syncthreads();
    int n = blockIdx.x * 256 + threadIdx.x;
    if (n < N_SRC) atomicAdd(&lc[ntype[n]], 1);
    __syncthreads();
    if (threadIdx.x < 8 && lc[threadIdx.x]) atomicAdd(&meta[threadIdx.x], lc[threadIdx.x]);
}

__global__ void plan_kernel(int* __restrict__ meta) {
    if (threadIdx.x == 0) {
        int total = 0;
        for (int t = 0; t < 8; ++t) {
            meta[8 + t] = total;                 // pos[t] = 64-padded offset
            total += ((meta[t] + 63) >> 6) << 6;
        }
    }
}

__global__ __launch_bounds__(256) void scatter_kernel(const int* __restrict__ ntype,
                                                      int* __restrict__ meta,
                                                      int* __restrict__ order) {
    __shared__ int lc[8], lb[8];
    int tid = threadIdx.x;
    if (tid < 8) lc[tid] = 0;
    __syncthreads();
    int n = blockIdx.x * 256 + tid;
    int t = 0, r = 0;
    bool ok = (n < N_SRC);
    if (ok) { t = ntype[n]; r = atomicAdd(&lc[t], 1); }
    __syncthreads();
    if (tid < 8) lb[tid] = lc[tid] ? atomicAdd(&meta[8 + tid], lc[tid]) : 0;
    __syncthreads();
    if (ok) order[lb[t] + r] = n;
}

// ----------------------------------------------- weight transpose to bf16
__global__ __launch_bounds__(256) void wprep_kernel(const float* __restrict__ Wk,
                                                    const float* __restrict__ Wq,
                                                    const float* __restrict__ Wv,
                                                    u16* __restrict__ Wt) {
    int blk = blockIdx.x;          // t3*8 + t
    int t3 = blk >> 3, t = blk & 7;
    const float* src = ((t3 == 0) ? Wk : ((t3 == 1) ? Wv : Wq)) + ((size_t)t << 14);
    u16* dst = Wt + ((size_t)blk << 14);
    for (int s = threadIdx.x; s < 16384; s += 256) {
        int n = s >> 7, k = s & 127;
        dst[n * 128 + k] = f2b(src[k * 128 + n]);
    }
}

// --------------------------------------- m_rel -> B-fragment layout (bf16)
// m_rel [et][h][d][f] fp32 -> Mp[h][f][et*32+d] bf16  (32768 elems, 64 KB)
__global__ __launch_bounds__(256) void mprep_kernel(const float* __restrict__ m_rel,
                                                    u16* __restrict__ Mp) {
    int i = blockIdx.x * 256 + threadIdx.x;
    int hh = i >> 13, f = (i >> 8) & 31, kk = i & 255;
    int et = kk >> 5, d = kk & 31;
    Mp[i] = f2b(m_rel[(size_t)((et * 4 + hh) * 32 + d) * 32 + f]);
}

// --------------------------------------- a_rel -> A-fragment layout (bf16)
// a_rel [et][h][d][f] fp32 -> Ap[h][d][et*32+f] bf16  (32768 elems, 64 KB)
__global__ __launch_bounds__(256) void aprep_kernel(const float* __restrict__ a_rel,
                                                    u16* __restrict__ Ap) {
    int i = blockIdx.x * 256 + threadIdx.x;
    int h = i >> 13, d = (i >> 8) & 31, et = (i >> 5) & 7, f = i & 31;
    Ap[i] = f2b(a_rel[(size_t)((et * 4 + h) * 32 + d) * 32 + f]);
}

// ------------------------------------------------------- MFMA typed linear
__global__ __launch_bounds__(256) void nl_mfma_kernel(
    const float* __restrict__ x, const int* __restrict__ ntype,
    const int* __restrict__ order, const u16* __restrict__ Wt,
    u16* __restrict__ K, u16* __restrict__ Q, u16* __restrict__ V) {
    __shared__ __align__(16) u16 Asm[64][136];  // row stride 272 B (68 words)
    __shared__ int rid[64];
    __shared__ int tsh, anyq;
    const int tid = threadIdx.x;
    const int r0 = blockIdx.x * 64;

    if (tid < 64) rid[tid] = order[r0 + tid];
    __syncthreads();
    if (tid == 0) {
        int t = -1, aq = 0;
        for (int i = 0; i < 64; ++i) {
            int id = rid[i];
            if (id >= 0) {
                if (t < 0) t = ntype[id];
                if (id < N_CTR) aq = 1;
            }
        }
        tsh = t; anyq = aq;
    }
    __syncthreads();
    const int t = tsh;
    if (t < 0) return;

    {   // stage A tile as bf16: thread -> (row, 32-col segment)
        int row = tid >> 2, seg = tid & 3;
        int id = rid[row];
        uint4 w[4];
        if (id >= 0) {
            const float4* xp = (const float4*)(x + (size_t)id * 128 + seg * 32);
#pragma unroll
            for (int q = 0; q < 4; ++q) {
                float4 va = xp[2 * q], vb = xp[2 * q + 1];
                w[q].x = (u32)f2b(va.x) | ((u32)f2b(va.y) << 16);
                w[q].y = (u32)f2b(va.z) | ((u32)f2b(va.w) << 16);
                w[q].z = (u32)f2b(vb.x) | ((u32)f2b(vb.y) << 16);
                w[q].w = (u32)f2b(vb.z) | ((u32)f2b(vb.w) << 16);
            }
        } else {
            uint4 z = {0u, 0u, 0u, 0u};
#pragma unroll
            for (int q = 0; q < 4; ++q) w[q] = z;
        }
        uint4* dst = (uint4*)&Asm[row][seg * 32];
#pragma unroll
        for (int q = 0; q < 4; ++q) dst[q] = w[q];
    }
    __syncthreads();

    const int lane = tid & 63;
    const int wv = tid >> 6;
    const int n0 = wv * 32;
    const int m  = lane & 31;
    const int kh = lane >> 5;

    for (int t3 = 0; t3 < 3; ++t3) {
        if (t3 == 2 && !anyq) continue;
        const u16* Bp = Wt + (((size_t)t3 * 8 + t) << 14) + (size_t)(n0 + m) * 128 + kh * 8;
        f32x16 acc0, acc1;
#pragma unroll
        for (int i = 0; i < 16; ++i) { acc0[i] = 0.f; acc1[i] = 0.f; }
#pragma unroll
        for (int kk = 0; kk < 8; ++kk) {
            bf16x8 b  = *(const bf16x8*)(Bp + kk * 16);
            bf16x8 a0 = *(const bf16x8*)&Asm[m][kk * 16 + kh * 8];
            bf16x8 a1 = *(const bf16x8*)&Asm[m + 32][kk * 16 + kh * 8];
            acc0 = __builtin_amdgcn_mfma_f32_32x32x16_bf16(a0, b, acc0, 0, 0, 0);
            acc1 = __builtin_amdgcn_mfma_f32_32x32x16_bf16(a1, b, acc1, 0, 0, 0);
        }
        u16* O = (t3 == 0) ? K : ((t3 == 1) ? V : Q);
#pragma unroll
        for (int r = 0; r < 16; ++r) {
            int row = (r & 3) + 8 * (r >> 2) + 4 * kh;
            int col = n0 + m;
            int g0 = rid[row], g1 = rid[row + 32];
            if (g0 >= 0 && (t3 != 2 || g0 < N_CTR)) O[(size_t)g0 * 128 + col] = f2b(acc0[r]);
            if (g1 >= 0 && (t3 != 2 || g1 < N_CTR)) O[(size_t)g1 * 128 + col] = f2b(acc1[r]);
        }
    }
}

// ------------------------------------------------------------ scores (MFMA)
// Block = 32 edges x 4 heads (wave = head). One-hot K-expansion over edge
// type: k = et*32+f (K=256, 16 mfma steps). A = Ap[h][d][k] (wave-uniform),
// B[k][e] = Q[e][f]*(et(e)==k>>5) (lane-local gate, 1 cmp + 4 cndmask).
// C = qw[d][e] with e = lane&31. Stage 2: per-lane 16-FMA dot with
// K[e][d(reg)] (4x8B gathers) + one shfl_xor(32). No LDS at all.
__global__ __launch_bounds__(256) void score_mfma_kernel(
    const u16* __restrict__ K, const u16* __restrict__ Q,
    const u16* __restrict__ Ap, const float* __restrict__ relp,
    const int* __restrict__ idx, const int* __restrict__ etype,
    const int* __restrict__ dstid, float* __restrict__ ascore) {
    const int tid = threadIdx.x;
    const int h = tid >> 6, l = tid & 63;
    const int lr = l & 31, kh = l >> 5;
    const int e = blockIdx.x * 32 + lr;          // 25000 blocks * 32 = N_EDGE

    const int src = idx[e], dst = dstid[e], et_e = etype[e];

    // Q octets for this lane's edge (f = (s&1)*16 + kh*8 + j)
    const u32* qp = (const u32*)(Q + (size_t)dst * 128 + h * 32 + kh * 8);
    u32 q0[4], q1[4];
#pragma unroll
    for (int j = 0; j < 4; ++j) { q0[j] = qp[j]; q1[j] = qp[8 + j]; }

    // K quads for stage 2 (d = (r&3) + 8*(r>>2) + 4*kh), issue early
    const u16* kb = K + (size_t)src * 128 + h * 32 + kh * 4;
    uint2 kv[4];
#pragma unroll
    for (int g = 0; g < 4; ++g) kv[g] = *(const uint2*)(kb + g * 8);

    f32x16 acc;
#pragma unroll
    for (int i = 0; i < 16; ++i) acc[i] = 0.f;

    const u16* ap = Ap + ((h * 32 + lr) << 8) + kh * 8;
#pragma unroll
    for (int s = 0; s < 16; ++s) {
        union { u32 u[4]; bf16x8 v; } fa, fb;
        *(uint4*)fa.u = *(const uint4*)(ap + s * 16);
        const bool sel = (et_e == (s >> 1));
        const u32* qq = (s & 1) ? q1 : q0;
#pragma unroll
        for (int j = 0; j < 4; ++j) fb.u[j] = sel ? qq[j] : 0u;
        acc = __builtin_amdgcn_mfma_f32_32x32x16_bf16(fa.v, fb.v, acc, 0, 0, 0);
    }

    // stage 2: s_e = sum_d K[e,d] * qw[d,e]
    float partial = 0.f;
#pragma unroll
    for (int g = 0; g < 4; ++g) {
        partial = fmaf(lo16(kv[g].x), acc[g * 4 + 0], partial);
        partial = fmaf(hi16(kv[g].x), acc[g * 4 + 1], partial);
        partial = fmaf(lo16(kv[g].y), acc[g * 4 + 2], partial);
        partial = fmaf(hi16(kv[g].y), acc[g * 4 + 3], partial);
    }
    float ssum = partial + __shfl_xor(partial, 32);
    if (kh == 0) {
        const float scale = 0.17677669529663687f;  // 1/sqrt(32)
        ascore[(size_t)h * N_EDGE + e] = ssum * relp[h * 8 + et_e] * scale;
    }
}

// ------------------------------------------- per-(center,head) softmax pre
// Edge-parallel over centers: m = segment max, inv = 1/segment sum of exp.
__global__ __launch_bounds__(256) void softmax_pre_kernel(
    const float* __restrict__ ascore, const int* __restrict__ ptr,
    float2* __restrict__ mden) {
    int c = blockIdx.x * 256 + threadIdx.x;
    int h = blockIdx.y;
    if (c >= N_CTR) return;
    int e0 = ptr[c], e1 = ptr[c + 1];
    const float* as = ascore + (size_t)h * N_EDGE;
    float m = -3.0e38f;
    for (int e = e0; e < e1; ++e) m = fmaxf(m, as[e]);
    float den = 0.f;
    for (int e = e0; e < e1; ++e) den += __expf(as[e] - m);
    float inv = (den > 0.f) ? 1.f / den : 0.f;
    mden[(size_t)c * 4 + h] = make_float2(m, inv);
}

// ---------------------------------------- aggregate (register one-hot MFMA)
// Block = 16 centers, 4 waves (wave = head h). Per 256-edge chunk: all
// threads stage per-edge metadata {src|bucket<<24, alpha[4] bf16} into a
// tiny LDS table (1 barrier), then each wave runs a barrier-free fragment
// loop over the chunk: per 16 edges build the B fragment by direct u16
// V-gathers (8 independent loads in flight) and 4 one-hot A fragments
// (alpha folded into the selector), 4 MFMA into acc[4] (128 bucket rows x
// 32 cols). Epilogue: buckets -> B16 LDS, then the unchanged Mp-transform.
#define CPB   16
#define CSTR  1032   // u16 per center row of B16 (1024 + 8 pad)
#define CHK   256    // edges staged per chunk
__global__ __launch_bounds__(256, 4) void aggregate_mfma_kernel(
    const u16* __restrict__ V, const u16* __restrict__ Mp,
    const float* __restrict__ ascore, const int* __restrict__ ptr,
    const int* __restrict__ idx, const int* __restrict__ etype,
    const int* __restrict__ dstid, const float2* __restrict__ mden,
    float* __restrict__ out) {
    __shared__ __align__(16) u16 B16[CPB * CSTR];   // 33024 B
    __shared__ u32 meta_sh[CHK];                    // src | bucket<<24
    __shared__ __align__(8) u16 alpha_sh[CHK][4];   // bf16 alpha per head

    const int tid = threadIdx.x;
    const int h = tid >> 6, l = tid & 63;
    const int lr = l & 31, kh = l >> 5;
    const int c0 = blockIdx.x * CPB;
    const int E0 = ptr[c0], E1 = ptr[c0 + CPB];
    const int dcol = h * 32 + lr;                   // this lane's V column

    f32x16 acc[4];
#pragma unroll
    for (int rb = 0; rb < 4; ++rb)
#pragma unroll
        for (int i = 0; i < 16; ++i) acc[rb][i] = 0.f;

    const int nch = (E1 - E0 + CHK - 1) / CHK;
    for (int ch = 0; ch < nch; ++ch) {
        const int eb = E0 + ch * CHK;
        {   // stage metadata + alpha for up to 256 edges (all 256 threads)
            int e = eb + tid;
            u32 mpk = 0xFFu << 24;   // sentinel bucket 255 -> never matches
            u32 a01 = 0u, a23 = 0u;
            if (e < E1) {
                int src = idx[e];
                int bkt = (dstid[e] - c0) * 8 + etype[e];
                mpk = (u32)src | ((u32)bkt << 24);
                const float4* md = (const float4*)(mden + (size_t)dstid[e] * 4);
                float4 mA = md[0], mB = md[1];
                float a0 = __expf(ascore[e] - mA.x) * mA.y;
                float a1 = __expf(ascore[N_EDGE + e] - mA.z) * mA.w;
                float a2 = __expf(ascore[2 * N_EDGE + e] - mB.x) * mB.y;
                float a3 = __expf(ascore[3 * N_EDGE + e] - mB.z) * mB.w;
                a01 = (u32)f2b(a0) | ((u32)f2b(a1) << 16);
                a23 = (u32)f2b(a2) | ((u32)f2b(a3) << 16);
            }
            meta_sh[tid] = mpk;
            *(uint2*)&alpha_sh[tid][0] = make_uint2(a01, a23);
        }
        __syncthreads();

        const int ce = min(CHK, E1 - eb);
        const int cloop = (ce + 15) & ~15;
        for (int s = 0; s < cloop; s += 16) {
            u32 bv[4], fa[4][4];
#pragma unroll
            for (int jj = 0; jj < 4; ++jj) {
                const int e2 = s + kh * 8 + 2 * jj;
                u32 m0 = meta_sh[e2], m1 = meta_sh[e2 + 1];
                u32 al0 = (u32)alpha_sh[e2][h];
                u32 ah1 = (u32)alpha_sh[e2 + 1][h] << 16;
                u32 v0 = (u32)V[(m0 & 0xFFFFFFu) * 128u + (u32)dcol];
                u32 v1 = (u32)V[(m1 & 0xFFFFFFu) * 128u + (u32)dcol];
                bv[jj] = v0 | (v1 << 16);
                int bl0 = (int)(m0 >> 24) - lr;
                int bl1 = (int)(m1 >> 24) - lr;
                fa[0][jj] = (bl0 == 0  ? al0 : 0u) | (bl1 == 0  ? ah1 : 0u);
                fa[1][jj] = (bl0 == 32 ? al0 : 0u) | (bl1 == 32 ? ah1 : 0u);
                fa[2][jj] = (bl0 == 64 ? al0 : 0u) | (bl1 == 64 ? ah1 : 0u);
                fa[3][jj] = (bl0 == 96 ? al0 : 0u) | (bl1 == 96 ? ah1 : 0u);
            }
            union { u32 u[4]; bf16x8 v; } fb;
#pragma unroll
            for (int j = 0; j < 4; ++j) fb.u[j] = bv[j];
#pragma unroll
            for (int rb = 0; rb < 4; ++rb) {
                union { u32 u[4]; bf16x8 v; } fav;
#pragma unroll
                for (int j = 0; j < 4; ++j) fav.u[j] = fa[rb][j];
                acc[rb] = __builtin_amdgcn_mfma_f32_32x32x16_bf16(fav.v, fb.v, acc[rb], 0, 0, 0);
            }
        }
        __syncthreads();   // protect meta/alpha for next chunk
    }

    // buckets -> B16 [center][et*128 + d]
#pragma unroll
    for (int rb = 0; rb < 4; ++rb) {
#pragma unroll
        for (int r = 0; r < 16; ++r) {
            const int g = 32 * rb + (r & 3) + 8 * (r >> 2) + 4 * kh;
            B16[(g >> 3) * CSTR + (g & 7) * 128 + h * 32 + lr] = f2b(acc[rb][r]);
        }
    }
    __syncthreads();

    // MFMA transform: wave h, both f-halves nt = 0,1 (unchanged math)
    const int mrow = l & 15, kq = l >> 4;
#pragma unroll
    for (int nt = 0; nt < 2; ++nt) {
        f32x4 acc2 = {0.f, 0.f, 0.f, 0.f};
        const u16* mp = Mp + h * 8192 + (nt * 16 + mrow) * 256 + kq * 8;
        const u16* ap = B16 + mrow * CSTR + h * 32 + kq * 8;
#pragma unroll
        for (int s = 0; s < 8; ++s) {
            bf16x8 a = *(const bf16x8*)(ap + s * 128);
            bf16x8 b = *(const bf16x8*)(mp + s * 32);
            acc2 = __builtin_amdgcn_mfma_f32_16x16x32_bf16(a, b, acc2, 0, 0, 0);
        }
#pragma unroll
        for (int r = 0; r < 4; ++r) {
            int c = c0 + kq * 4 + r;
            out[(size_t)c * 128 + h * 32 + nt * 16 + mrow] = acc2[r];
        }
    }
}

// ---------------------------------------------------------------- launch
extern "C" void kernel_launch(void* const* d_in, const int* in_sizes, int n_in,
                              void* d_out, int out_size, void* d_ws, size_t ws_size,
                              hipStream_t stream) {
    const float* x     = (const float*)d_in[0];
    const int*   ptr   = (const int*)d_in[1];
    const int*   idx   = (const int*)d_in[2];
    const int*   ntype = (const int*)d_in[3];
    const int*   etype = (const int*)d_in[4];
    const float* k_lin = (const float*)d_in[8];
    const float* q_lin = (const float*)d_in[9];
    const float* v_lin = (const float*)d_in[10];
    const float* a_rel = (const float*)d_in[11];
    const float* m_rel = (const float*)d_in[12];
    const float* relp  = (const float*)d_in[13];
    float* out = (float*)d_out;

    // ws layout (ws_size >= 272 MB established round 2)
    char* ws = (char*)d_ws;
    u16*   Kb    = (u16*)(ws);                  // 51.2 MB
    u16*   Vb    = (u16*)(ws + 51200000);       // 51.2 MB
    u16*   Qb    = (u16*)(ws + 102400000);      // 25.6 MB
    float* As    = (float*)(ws + 128000000);    // 12.8 MB ([4][N_EDGE])
    int*   dstid = (int*)(ws + 140800000);      // 3.2 MB
    u16*   Wt    = (u16*)(ws + 144000000);      // 786,432 B
    int*   meta  = (int*)(ws + 144786432);      // 64 B
    int*   order = (int*)(ws + 144786496);      // 802,816 B
    u16*   Mp    = (u16*)(ws + 145589312);      // 65,536 B
    float2* mden = (float2*)(ws + 145654848);   // 3.2 MB ([N_CTR][4])
    u16*   Apb   = (u16*)(ws + 148854848);      // 65,536 B

    dstfill_kernel<<<391, 256, 0, stream>>>(ptr, dstid);
    fillzero_kernel<<<784, 256, 0, stream>>>(order, meta);
    wprep_kernel<<<24, 256, 0, stream>>>(k_lin, q_lin, v_lin, Wt);
    mprep_kernel<<<128, 256, 0, stream>>>(m_rel, Mp);
    aprep_kernel<<<128, 256, 0, stream>>>(a_rel, Apb);
    hist_kernel<<<782, 256, 0, stream>>>(ntype, meta);
    plan_kernel<<<1, 64, 0, stream>>>(meta);
    scatter_kernel<<<782, 256, 0, stream>>>(ntype, meta, order);
    nl_mfma_kernel<<<NBLK, 256, 0, stream>>>(x, ntype, order, Wt, Kb, Qb, Vb);
    score_mfma_kernel<<<25000, 256, 0, stream>>>(Kb, Qb, Apb, relp, idx, etype, dstid, As);
    softmax_pre_kernel<<<dim3(391, 4), 256, 0, stream>>>(As, ptr, mden);
    aggregate_mfma_kernel<<<6250, 256, 0, stream>>>(Vb, Mp, As, ptr, idx, etype, dstid, mden, out);
}

// Round 5
// 531.712 us; speedup vs baseline: 1.2604x; 1.2604x over previous
//
#include <hip/hip_runtime.h>

typedef unsigned int u32;
typedef unsigned short u16;
typedef __bf16 bf16x8 __attribute__((ext_vector_type(8)));
typedef float f32x4 __attribute__((ext_vector_type(4)));
typedef float f32x16 __attribute__((ext_vector_type(16)));

#define N_SRC 200000
#define N_CTR 100000
#define N_EDGE 800000
#define NBLK 3136  // >= sum_t ceil(cnt_t/64) <= 3133

__device__ __forceinline__ float lo16(u32 u) { return __uint_as_float(u << 16); }
__device__ __forceinline__ float hi16(u32 u) { return __uint_as_float(u & 0xFFFF0000u); }
__device__ __forceinline__ u16 f2b(float f) {
    u32 u = __float_as_uint(f);
    u32 r = (u + 0x7FFFu + ((u >> 16) & 1u)) >> 16;
    return (u16)r;
}

// ---------------------------------------------------------------- dst fill
__global__ __launch_bounds__(256) void dstfill_kernel(const int* __restrict__ ptr,
                                                      int* __restrict__ dst) {
    int c = blockIdx.x * 256 + threadIdx.x;
    if (c < N_CTR) {
        int e1 = ptr[c + 1];
        for (int e = ptr[c]; e < e1; ++e) dst[e] = c;
    }
}

// ---------------------------------------------------- grouping machinery
__global__ __launch_bounds__(256) void fillzero_kernel(int* __restrict__ order,
                                                       int* __restrict__ meta) {
    int i = blockIdx.x * 256 + threadIdx.x;
    if (i < NBLK * 64) order[i] = -1;
    if (blockIdx.x == 0 && threadIdx.x < 16) meta[threadIdx.x] = 0;
}

__global__ __launch_bounds__(256) void hist_kernel(const int* __restrict__ ntype,
                                                   int* __restrict__ meta) {
    __shared__ int lc[8];
    if (threadIdx.x < 8) lc[threadIdx.x] = 0;
    __syncthreads();
    int n = blockIdx.x * 256 + threadIdx.x;
    if (n < N_SRC) atomicAdd(&lc[ntype[n]], 1);
    __syncthreads();
    if (threadIdx.x < 8 && lc[threadIdx.x]) atomicAdd(&meta[threadIdx.x], lc[threadIdx.x]);
}

__global__ void plan_kernel(int* __restrict__ meta) {
    if (threadIdx.x == 0) {
        int total = 0;
        for (int t = 0; t < 8; ++t) {
            meta[8 + t] = total;                 // pos[t] = 64-padded offset
            total += ((meta[t] + 63) >> 6) << 6;
        }
    }
}

__global__ __launch_bounds__(256) void scatter_kernel(const int* __restrict__ ntype,
                                                      int* __restrict__ meta,
                                                      int* __restrict__ order) {
    __shared__ int lc[8], lb[8];
    int tid = threadIdx.x;
    if (tid < 8) lc[tid] = 0;
    __syncthreads();
    int n = blockIdx.x * 256 + tid;
    int t = 0, r = 0;
    bool ok = (n < N_SRC);
    if (ok) { t = ntype[n]; r = atomicAdd(&lc[t], 1); }
    __syncthreads();
    if (tid < 8) lb[tid] = lc[tid] ? atomicAdd(&meta[8 + tid], lc[tid]) : 0;
    __syncthreads();
    if (ok) order[lb[t] + r] = n;
}

// ----------------------------------------------- weight transpose to bf16
__global__ __launch_bounds__(256) void wprep_kernel(const float* __restrict__ Wk,
                                                    const float* __restrict__ Wq,
                                                    const float* __restrict__ Wv,
                                                    u16* __restrict__ Wt) {
    int blk = blockIdx.x;          // t3*8 + t
    int t3 = blk >> 3, t = blk & 7;
    const float* src = ((t3 == 0) ? Wk : ((t3 == 1) ? Wv : Wq)) + ((size_t)t << 14);
    u16* dst = Wt + ((size_t)blk << 14);
    for (int s = threadIdx.x; s < 16384; s += 256) {
        int n = s >> 7, k = s & 127;
        dst[n * 128 + k] = f2b(src[k * 128 + n]);
    }
}

// --------------------------------------- m_rel -> B-fragment layout (bf16)
// m_rel [et][h][d][f] fp32 -> Mp[h][f][et*32+d] bf16  (32768 elems, 64 KB)
__global__ __launch_bounds__(256) void mprep_kernel(const float* __restrict__ m_rel,
                                                    u16* __restrict__ Mp) {
    int i = blockIdx.x * 256 + threadIdx.x;
    int hh = i >> 13, f = (i >> 8) & 31, kk = i & 255;
    int et = kk >> 5, d = kk & 31;
    Mp[i] = f2b(m_rel[(size_t)((et * 4 + hh) * 32 + d) * 32 + f]);
}

// --------------------------------------- a_rel -> A-fragment layout (bf16)
// a_rel [et][h][d][f] fp32 -> Ap[h][d][et*32+f] bf16  (32768 elems, 64 KB)
__global__ __launch_bounds__(256) void aprep_kernel(const float* __restrict__ a_rel,
                                                    u16* __restrict__ Ap) {
    int i = blockIdx.x * 256 + threadIdx.x;
    int h = i >> 13, d = (i >> 8) & 31, et = (i >> 5) & 7, f = i & 31;
    Ap[i] = f2b(a_rel[(size_t)((et * 4 + h) * 32 + d) * 32 + f]);
}

// ------------------------------------------------------- MFMA typed linear
__global__ __launch_bounds__(256) void nl_mfma_kernel(
    const float* __restrict__ x, const int* __restrict__ ntype,
    const int* __restrict__ order, const u16* __restrict__ Wt,
    u16* __restrict__ K, u16* __restrict__ Q, u16* __restrict__ V) {
    __shared__ __align__(16) u16 Asm[64][136];  // row stride 272 B (68 words)
    __shared__ int rid[64];
    __shared__ int tsh, anyq;
    const int tid = threadIdx.x;
    const int r0 = blockIdx.x * 64;

    if (tid < 64) rid[tid] = order[r0 + tid];
    __syncthreads();
    if (tid == 0) {
        int t = -1, aq = 0;
        for (int i = 0; i < 64; ++i) {
            int id = rid[i];
            if (id >= 0) {
                if (t < 0) t = ntype[id];
                if (id < N_CTR) aq = 1;
            }
        }
        tsh = t; anyq = aq;
    }
    __syncthreads();
    const int t = tsh;
    if (t < 0) return;

    {   // stage A tile as bf16: thread -> (row, 32-col segment)
        int row = tid >> 2, seg = tid & 3;
        int id = rid[row];
        uint4 w[4];
        if (id >= 0) {
            const float4* xp = (const float4*)(x + (size_t)id * 128 + seg * 32);
#pragma unroll
            for (int q = 0; q < 4; ++q) {
                float4 va = xp[2 * q], vb = xp[2 * q + 1];
                w[q].x = (u32)f2b(va.x) | ((u32)f2b(va.y) << 16);
                w[q].y = (u32)f2b(va.z) | ((u32)f2b(va.w) << 16);
                w[q].z = (u32)f2b(vb.x) | ((u32)f2b(vb.y) << 16);
                w[q].w = (u32)f2b(vb.z) | ((u32)f2b(vb.w) << 16);
            }
        } else {
            uint4 z = {0u, 0u, 0u, 0u};
#pragma unroll
            for (int q = 0; q < 4; ++q) w[q] = z;
        }
        uint4* dst = (uint4*)&Asm[row][seg * 32];
#pragma unroll
        for (int q = 0; q < 4; ++q) dst[q] = w[q];
    }
    __syncthreads();

    const int lane = tid & 63;
    const int wv = tid >> 6;
    const int n0 = wv * 32;
    const int m  = lane & 31;
    const int kh = lane >> 5;

    for (int t3 = 0; t3 < 3; ++t3) {
        if (t3 == 2 && !anyq) continue;
        const u16* Bp = Wt + (((size_t)t3 * 8 + t) << 14) + (size_t)(n0 + m) * 128 + kh * 8;
        f32x16 acc0, acc1;
#pragma unroll
        for (int i = 0; i < 16; ++i) { acc0[i] = 0.f; acc1[i] = 0.f; }
#pragma unroll
        for (int kk = 0; kk < 8; ++kk) {
            bf16x8 b  = *(const bf16x8*)(Bp + kk * 16);
            bf16x8 a0 = *(const bf16x8*)&Asm[m][kk * 16 + kh * 8];
            bf16x8 a1 = *(const bf16x8*)&Asm[m + 32][kk * 16 + kh * 8];
            acc0 = __builtin_amdgcn_mfma_f32_32x32x16_bf16(a0, b, acc0, 0, 0, 0);
            acc1 = __builtin_amdgcn_mfma_f32_32x32x16_bf16(a1, b, acc1, 0, 0, 0);
        }
        u16* O = (t3 == 0) ? K : ((t3 == 1) ? V : Q);
#pragma unroll
        for (int r = 0; r < 16; ++r) {
            int row = (r & 3) + 8 * (r >> 2) + 4 * kh;
            int col = n0 + m;
            int g0 = rid[row], g1 = rid[row + 32];
            if (g0 >= 0 && (t3 != 2 || g0 < N_CTR)) O[(size_t)g0 * 128 + col] = f2b(acc0[r]);
            if (g1 >= 0 && (t3 != 2 || g1 < N_CTR)) O[(size_t)g1 * 128 + col] = f2b(acc1[r]);
        }
    }
}

// ------------------------------------------------------------ scores (MFMA)
// Block = 256 edges (8 tiles of 32) x 4 heads (wave = head). A-fragments
// (Ap[h][d][et*32+f], 16 x uint4 = 64 VGPR) are loaded ONCE per wave and
// statically indexed; the tile loop re-uses them for 8 edge-tiles,
// removing the dominant per-tile L2 gather (was 512 line-touches/wave).
// Per tile: coalesced meta, Q 2x16B + K 4x8B gathers, 16 reg-fed MFMAs
// (B gated by et one-hot), per-lane 16-FMA stage-2 dot + shfl_xor(32).
#define STILE 8
__global__ __launch_bounds__(256, 4) void score_mfma_kernel(
    const u16* __restrict__ K, const u16* __restrict__ Q,
    const u16* __restrict__ Ap, const float* __restrict__ relp,
    const int* __restrict__ idx, const int* __restrict__ etype,
    const int* __restrict__ dstid, float* __restrict__ ascore) {
    const int tid = threadIdx.x;
    const int h = tid >> 6, l = tid & 63;
    const int lr = l & 31, kh = l >> 5;
    const int e0 = blockIdx.x * (32 * STILE);    // 3125 blocks * 256 = N_EDGE

    // A-fragments: row d = lr, k = s*16 + kh*8 + j  (static indexing!)
    const u16* ap = Ap + ((h * 32 + lr) << 8) + kh * 8;
    uint4 fa[16];
#pragma unroll
    for (int s = 0; s < 16; ++s) fa[s] = *(const uint4*)(ap + s * 16);

    const float scale = 0.17677669529663687f;    // 1/sqrt(32)

    for (int t = 0; t < STILE; ++t) {
        const int e = e0 + t * 32 + lr;
        const int src = idx[e], dst = dstid[e], et_e = etype[e];

        // Q octets (f = (s&1)*16 + kh*8 + j)
        const u32* qp = (const u32*)(Q + (size_t)dst * 128 + h * 32 + kh * 8);
        u32 q0[4], q1[4];
#pragma unroll
        for (int j = 0; j < 4; ++j) { q0[j] = qp[j]; q1[j] = qp[8 + j]; }

        // K quads for stage 2 (d = (r&3) + 8*(r>>2) + 4*kh)
        const u16* kb = K + (size_t)src * 128 + h * 32 + kh * 4;
        uint2 kv[4];
#pragma unroll
        for (int g = 0; g < 4; ++g) kv[g] = *(const uint2*)(kb + g * 8);

        f32x16 acc;
#pragma unroll
        for (int i = 0; i < 16; ++i) acc[i] = 0.f;

#pragma unroll
        for (int s = 0; s < 16; ++s) {
            union { u32 u[4]; bf16x8 v; } fav, fb;
            fav.u[0] = fa[s].x; fav.u[1] = fa[s].y;
            fav.u[2] = fa[s].z; fav.u[3] = fa[s].w;
            const bool sel = (et_e == (s >> 1));
            const u32* qq = (s & 1) ? q1 : q0;
#pragma unroll
            for (int j = 0; j < 4; ++j) fb.u[j] = sel ? qq[j] : 0u;
            acc = __builtin_amdgcn_mfma_f32_32x32x16_bf16(fav.v, fb.v, acc, 0, 0, 0);
        }

        // stage 2: s_e = sum_d K[e,d] * qw[d,e]
        float partial = 0.f;
#pragma unroll
        for (int g = 0; g < 4; ++g) {
            partial = fmaf(lo16(kv[g].x), acc[g * 4 + 0], partial);
            partial = fmaf(hi16(kv[g].x), acc[g * 4 + 1], partial);
            partial = fmaf(lo16(kv[g].y), acc[g * 4 + 2], partial);
            partial = fmaf(hi16(kv[g].y), acc[g * 4 + 3], partial);
        }
        float ssum = partial + __shfl_xor(partial, 32);
        if (kh == 0) {
            ascore[(size_t)h * N_EDGE + e] = ssum * relp[h * 8 + et_e] * scale;
        }
    }
}

// ------------------------------------------- per-(center,head) softmax pre
// Edge-parallel over centers: m = segment max, inv = 1/segment sum of exp.
__global__ __launch_bounds__(256) void softmax_pre_kernel(
    const float* __restrict__ ascore, const int* __restrict__ ptr,
    float2* __restrict__ mden) {
    int c = blockIdx.x * 256 + threadIdx.x;
    int h = blockIdx.y;
    if (c >= N_CTR) return;
    int e0 = ptr[c], e1 = ptr[c + 1];
    const float* as = ascore + (size_t)h * N_EDGE;
    float m = -3.0e38f;
    for (int e = e0; e < e1; ++e) m = fmaxf(m, as[e]);
    float den = 0.f;
    for (int e = e0; e < e1; ++e) den += __expf(as[e] - m);
    float inv = (den > 0.f) ? 1.f / den : 0.f;
    mden[(size_t)c * 4 + h] = make_float2(m, inv);
}

// ---------------------------------------- aggregate (register one-hot MFMA)
// Block = 16 centers, 4 waves (wave = head h). Per 256-edge chunk: all
// threads stage per-edge metadata {src|bucket<<24, alpha[4] bf16} into a
// tiny LDS table (1 barrier), then each wave runs a barrier-free fragment
// loop over the chunk: per 16 edges build the B fragment by direct u16
// V-gathers (8 independent loads in flight) and 4 one-hot A fragments
// (alpha folded into the selector), 4 MFMA into acc[4] (128 bucket rows x
// 32 cols). Epilogue: buckets -> B16 LDS, then the unchanged Mp-transform.
#define CPB   16
#define CSTR  1032   // u16 per center row of B16 (1024 + 8 pad)
#define CHK   256    // edges staged per chunk
__global__ __launch_bounds__(256, 4) void aggregate_mfma_kernel(
    const u16* __restrict__ V, const u16* __restrict__ Mp,
    const float* __restrict__ ascore, const int* __restrict__ ptr,
    const int* __restrict__ idx, const int* __restrict__ etype,
    const int* __restrict__ dstid, const float2* __restrict__ mden,
    float* __restrict__ out) {
    __shared__ __align__(16) u16 B16[CPB * CSTR];   // 33024 B
    __shared__ u32 meta_sh[CHK];                    // src | bucket<<24
    __shared__ __align__(8) u16 alpha_sh[CHK][4];   // bf16 alpha per head

    const int tid = threadIdx.x;
    const int h = tid >> 6, l = tid & 63;
    const int lr = l & 31, kh = l >> 5;
    const int c0 = blockIdx.x * CPB;
    const int E0 = ptr[c0], E1 = ptr[c0 + CPB];
    const int dcol = h * 32 + lr;                   // this lane's V column

    f32x16 acc[4];
#pragma unroll
    for (int rb = 0; rb < 4; ++rb)
#pragma unroll
        for (int i = 0; i < 16; ++i) acc[rb][i] = 0.f;

    const int nch = (E1 - E0 + CHK - 1) / CHK;
    for (int ch = 0; ch < nch; ++ch) {
        const int eb = E0 + ch * CHK;
        {   // stage metadata + alpha for up to 256 edges (all 256 threads)
            int e = eb + tid;
            u32 mpk = 0xFFu << 24;   // sentinel bucket 255 -> never matches
            u32 a01 = 0u, a23 = 0u;
            if (e < E1) {
                int src = idx[e];
                int bkt = (dstid[e] - c0) * 8 + etype[e];
                mpk = (u32)src | ((u32)bkt << 24);
                const float4* md = (const float4*)(mden + (size_t)dstid[e] * 4);
                float4 mA = md[0], mB = md[1];
                float a0 = __expf(ascore[e] - mA.x) * mA.y;
                float a1 = __expf(ascore[N_EDGE + e] - mA.z) * mA.w;
                float a2 = __expf(ascore[2 * N_EDGE + e] - mB.x) * mB.y;
                float a3 = __expf(ascore[3 * N_EDGE + e] - mB.z) * mB.w;
                a01 = (u32)f2b(a0) | ((u32)f2b(a1) << 16);
                a23 = (u32)f2b(a2) | ((u32)f2b(a3) << 16);
            }
            meta_sh[tid] = mpk;
            *(uint2*)&alpha_sh[tid][0] = make_uint2(a01, a23);
        }
        __syncthreads();

        const int ce = min(CHK, E1 - eb);
        const int cloop = (ce + 15) & ~15;
        for (int s = 0; s < cloop; s += 16) {
            u32 bv[4], fa[4][4];
#pragma unroll
            for (int jj = 0; jj < 4; ++jj) {
                const int e2 = s + kh * 8 + 2 * jj;
                u32 m0 = meta_sh[e2], m1 = meta_sh[e2 + 1];
                u32 al0 = (u32)alpha_sh[e2][h];
                u32 ah1 = (u32)alpha_sh[e2 + 1][h] << 16;
                u32 v0 = (u32)V[(m0 & 0xFFFFFFu) * 128u + (u32)dcol];
                u32 v1 = (u32)V[(m1 & 0xFFFFFFu) * 128u + (u32)dcol];
                bv[jj] = v0 | (v1 << 16);
                int bl0 = (int)(m0 >> 24) - lr;
                int bl1 = (int)(m1 >> 24) - lr;
                fa[0][jj] = (bl0 == 0  ? al0 : 0u) | (bl1 == 0  ? ah1 : 0u);
                fa[1][jj] = (bl0 == 32 ? al0 : 0u) | (bl1 == 32 ? ah1 : 0u);
                fa[2][jj] = (bl0 == 64 ? al0 : 0u) | (bl1 == 64 ? ah1 : 0u);
                fa[3][jj] = (bl0 == 96 ? al0 : 0u) | (bl1 == 96 ? ah1 : 0u);
            }
            union { u32 u[4]; bf16x8 v; } fb;
#pragma unroll
            for (int j = 0; j < 4; ++j) fb.u[j] = bv[j];
#pragma unroll
            for (int rb = 0; rb < 4; ++rb) {
                union { u32 u[4]; bf16x8 v; } fav;
#pragma unroll
                for (int j = 0; j < 4; ++j) fav.u[j] = fa[rb][j];
                acc[rb] = __builtin_amdgcn_mfma_f32_32x32x16_bf16(fav.v, fb.v, acc[rb], 0, 0, 0);
            }
        }
        __syncthreads();   // protect meta/alpha for next chunk
    }

    // buckets -> B16 [center][et*128 + d]
#pragma unroll
    for (int rb = 0; rb < 4; ++rb) {
#pragma unroll
        for (int r = 0; r < 16; ++r) {
            const int g = 32 * rb + (r & 3) + 8 * (r >> 2) + 4 * kh;
            B16[(g >> 3) * CSTR + (g & 7) * 128 + h * 32 + lr] = f2b(acc[rb][r]);
        }
    }
    __syncthreads();

    // MFMA transform: wave h, both f-halves nt = 0,1 (unchanged math)
    const int mrow = l & 15, kq = l >> 4;
#pragma unroll
    for (int nt = 0; nt < 2; ++nt) {
        f32x4 acc2 = {0.f, 0.f, 0.f, 0.f};
        const u16* mp = Mp + h * 8192 + (nt * 16 + mrow) * 256 + kq * 8;
        const u16* ap = B16 + mrow * CSTR + h * 32 + kq * 8;
#pragma unroll
        for (int s = 0; s < 8; ++s) {
            bf16x8 a = *(const bf16x8*)(ap + s * 128);
            bf16x8 b = *(const bf16x8*)(mp + s * 32);
            acc2 = __builtin_amdgcn_mfma_f32_16x16x32_bf16(a, b, acc2, 0, 0, 0);
        }
#pragma unroll
        for (int r = 0; r < 4; ++r) {
            int c = c0 + kq * 4 + r;
            out[(size_t)c * 128 + h * 32 + nt * 16 + mrow] = acc2[r];
        }
    }
}

// ---------------------------------------------------------------- launch
extern "C" void kernel_launch(void* const* d_in, const int* in_sizes, int n_in,
                              void* d_out, int out_size, void* d_ws, size_t ws_size,
                              hipStream_t stream) {
    const float* x     = (const float*)d_in[0];
    const int*   ptr   = (const int*)d_in[1];
    const int*   idx   = (const int*)d_in[2];
    const int*   ntype = (const int*)d_in[3];
    const int*   etype = (const int*)d_in[4];
    const float* k_lin = (const float*)d_in[8];
    const float* q_lin = (const float*)d_in[9];
    const float* v_lin = (const float*)d_in[10];
    const float* a_rel = (const float*)d_in[11];
    const float* m_rel = (const float*)d_in[12];
    const float* relp  = (const float*)d_in[13];
    float* out = (float*)d_out;

    // ws layout (ws_size >= 272 MB established round 2)
    char* ws = (char*)d_ws;
    u16*   Kb    = (u16*)(ws);                  // 51.2 MB
    u16*   Vb    = (u16*)(ws + 51200000);       // 51.2 MB
    u16*   Qb    = (u16*)(ws + 102400000);      // 25.6 MB
    float* As    = (float*)(ws + 128000000);    // 12.8 MB ([4][N_EDGE])
    int*   dstid = (int*)(ws + 140800000);      // 3.2 MB
    u16*   Wt    = (u16*)(ws + 144000000);      // 786,432 B
    int*   meta  = (int*)(ws + 144786432);      // 64 B
    int*   order = (int*)(ws + 144786496);      // 802,816 B
    u16*   Mp    = (u16*)(ws + 145589312);      // 65,536 B
    float2* mden = (float2*)(ws + 145654848);   // 3.2 MB ([N_CTR][4])
    u16*   Apb   = (u16*)(ws + 148854848);      // 65,536 B

    dstfill_kernel<<<391, 256, 0, stream>>>(ptr, dstid);
    fillzero_kernel<<<784, 256, 0, stream>>>(order, meta);
    wprep_kernel<<<24, 256, 0, stream>>>(k_lin, q_lin, v_lin, Wt);
    mprep_kernel<<<128, 256, 0, stream>>>(m_rel, Mp);
    aprep_kernel<<<128, 256, 0, stream>>>(a_rel, Apb);
    hist_kernel<<<782, 256, 0, stream>>>(ntype, meta);
    plan_kernel<<<1, 64, 0, stream>>>(meta);
    scatter_kernel<<<782, 256, 0, stream>>>(ntype, meta, order);
    nl_mfma_kernel<<<NBLK, 256, 0, stream>>>(x, ntype, order, Wt, Kb, Qb, Vb);
    score_mfma_kernel<<<3125, 256, 0, stream>>>(Kb, Qb, Apb, relp, idx, etype, dstid, As);
    softmax_pre_kernel<<<dim3(391, 4), 256, 0, stream>>>(As, ptr, mden);
    aggregate_mfma_kernel<<<6250, 256, 0, stream>>>(Vb, Mp, As, ptr, idx, etype, dstid, mden, out);
}

// Round 6
// 504.886 us; speedup vs baseline: 1.3274x; 1.0531x over previous
//
#include <hip/hip_runtime.h>

typedef unsigned int u32;
typedef unsigned short u16;
typedef __bf16 bf16x8 __attribute__((ext_vector_type(8)));
typedef float f32x4 __attribute__((ext_vector_type(4)));
typedef float f32x16 __attribute__((ext_vector_type(16)));

#define N_SRC 200000
#define N_CTR 100000
#define N_EDGE 800000
#define NBLK 3136  // >= sum_t ceil(cnt_t/64) <= 3133

__device__ __forceinline__ float lo16(u32 u) { return __uint_as_float(u << 16); }
__device__ __forceinline__ float hi16(u32 u) { return __uint_as_float(u & 0xFFFF0000u); }
__device__ __forceinline__ u16 f2b(float f) {
    u32 u = __float_as_uint(f);
    u32 r = (u + 0x7FFFu + ((u >> 16) & 1u)) >> 16;
    return (u16)r;
}

// ---------------------------------------------------------------- dst fill
__global__ __launch_bounds__(256) void dstfill_kernel(const int* __restrict__ ptr,
                                                      int* __restrict__ dst) {
    int c = blockIdx.x * 256 + threadIdx.x;
    if (c < N_CTR) {
        int e1 = ptr[c + 1];
        for (int e = ptr[c]; e < e1; ++e) dst[e] = c;
    }
}

// ---------------------------------------------------- grouping machinery
__global__ __launch_bounds__(256) void fillzero_kernel(int* __restrict__ order,
                                                       int* __restrict__ meta) {
    int i = blockIdx.x * 256 + threadIdx.x;
    if (i < NBLK * 64) order[i] = -1;
    if (blockIdx.x == 0 && threadIdx.x < 16) meta[threadIdx.x] = 0;
}

__global__ __launch_bounds__(256) void hist_kernel(const int* __restrict__ ntype,
                                                   int* __restrict__ meta) {
    __shared__ int lc[8];
    if (threadIdx.x < 8) lc[threadIdx.x] = 0;
    __syncthreads();
    int n = blockIdx.x * 256 + threadIdx.x;
    if (n < N_SRC) atomicAdd(&lc[ntype[n]], 1);
    __syncthreads();
    if (threadIdx.x < 8 && lc[threadIdx.x]) atomicAdd(&meta[threadIdx.x], lc[threadIdx.x]);
}

__global__ void plan_kernel(int* __restrict__ meta) {
    if (threadIdx.x == 0) {
        int total = 0;
        for (int t = 0; t < 8; ++t) {
            meta[8 + t] = total;                 // pos[t] = 64-padded offset
            total += ((meta[t] + 63) >> 6) << 6;
        }
    }
}

__global__ __launch_bounds__(256) void scatter_kernel(const int* __restrict__ ntype,
                                                      int* __restrict__ meta,
                                                      int* __restrict__ order) {
    __shared__ int lc[8], lb[8];
    int tid = threadIdx.x;
    if (tid < 8) lc[tid] = 0;
    __syncthreads();
    int n = blockIdx.x * 256 + tid;
    int t = 0, r = 0;
    bool ok = (n < N_SRC);
    if (ok) { t = ntype[n]; r = atomicAdd(&lc[t], 1); }
    __syncthreads();
    if (tid < 8) lb[tid] = lc[tid] ? atomicAdd(&meta[8 + tid], lc[tid]) : 0;
    __syncthreads();
    if (ok) order[lb[t] + r] = n;
}

// ----------------------------------------------- weight transpose to bf16
__global__ __launch_bounds__(256) void wprep_kernel(const float* __restrict__ Wk,
                                                    const float* __restrict__ Wq,
                                                    const float* __restrict__ Wv,
                                                    u16* __restrict__ Wt) {
    int blk = blockIdx.x;          // t3*8 + t
    int t3 = blk >> 3, t = blk & 7;
    const float* src = ((t3 == 0) ? Wk : ((t3 == 1) ? Wv : Wq)) + ((size_t)t << 14);
    u16* dst = Wt + ((size_t)blk << 14);
    for (int s = threadIdx.x; s < 16384; s += 256) {
        int n = s >> 7, k = s & 127;
        dst[n * 128 + k] = f2b(src[k * 128 + n]);
    }
}

// --------------------------------------- m_rel -> B-fragment layout (bf16)
// m_rel [et][h][d][f] fp32 -> Mp[h][f][et*32+d] bf16  (32768 elems, 64 KB)
__global__ __launch_bounds__(256) void mprep_kernel(const float* __restrict__ m_rel,
                                                    u16* __restrict__ Mp) {
    int i = blockIdx.x * 256 + threadIdx.x;
    int hh = i >> 13, f = (i >> 8) & 31, kk = i & 255;
    int et = kk >> 5, d = kk & 31;
    Mp[i] = f2b(m_rel[(size_t)((et * 4 + hh) * 32 + d) * 32 + f]);
}

// --------------------------------------- a_rel -> A-fragment layout (bf16)
// a_rel [et][h][d][f] fp32 -> Ap[h][d][et*32+f] bf16  (32768 elems, 64 KB)
__global__ __launch_bounds__(256) void aprep_kernel(const float* __restrict__ a_rel,
                                                    u16* __restrict__ Ap) {
    int i = blockIdx.x * 256 + threadIdx.x;
    int h = i >> 13, d = (i >> 8) & 31, et = (i >> 5) & 7, f = i & 31;
    Ap[i] = f2b(a_rel[(size_t)((et * 4 + h) * 32 + d) * 32 + f]);
}

// ------------------------------------------------------- MFMA typed linear
__global__ __launch_bounds__(256) void nl_mfma_kernel(
    const float* __restrict__ x, const int* __restrict__ ntype,
    const int* __restrict__ order, const u16* __restrict__ Wt,
    u16* __restrict__ K, u16* __restrict__ Q, u16* __restrict__ V) {
    __shared__ __align__(16) u16 Asm[64][136];  // row stride 272 B (68 words)
    __shared__ int rid[64];
    __shared__ int tsh, anyq;
    const int tid = threadIdx.x;
    const int r0 = blockIdx.x * 64;

    if (tid < 64) rid[tid] = order[r0 + tid];
    __syncthreads();

    {   // stage A tile as bf16: thread -> (row, 32-col segment).
        // Issued BEFORE the type scan so the x-row gather latency overlaps
        // the single ntype load; one barrier covers both.
        int row = tid >> 2, seg = tid & 3;
        int id = rid[row];
        uint4 w[4];
        if (id >= 0) {
            const float4* xp = (const float4*)(x + (size_t)id * 128 + seg * 32);
#pragma unroll
            for (int q = 0; q < 4; ++q) {
                float4 va = xp[2 * q], vb = xp[2 * q + 1];
                w[q].x = (u32)f2b(va.x) | ((u32)f2b(va.y) << 16);
                w[q].y = (u32)f2b(va.z) | ((u32)f2b(va.w) << 16);
                w[q].z = (u32)f2b(vb.x) | ((u32)f2b(vb.y) << 16);
                w[q].w = (u32)f2b(vb.z) | ((u32)f2b(vb.w) << 16);
            }
        } else {
            uint4 z = {0u, 0u, 0u, 0u};
#pragma unroll
            for (int q = 0; q < 4; ++q) w[q] = z;
        }
        uint4* dst = (uint4*)&Asm[row][seg * 32];
#pragma unroll
        for (int q = 0; q < 4; ++q) dst[q] = w[q];
    }

    // wave-parallel type scan: all valid rows share one type by construction
    // (order is grouped by type, 64-padded) -> ballot + ONE ntype load.
    if (tid < 64) {
        int id = rid[tid];
        unsigned long long mv = __ballot(id >= 0);
        unsigned long long mq = __ballot(id >= 0 && id < N_CTR);
        if (tid == 0) anyq = (mq != 0ull) ? 1 : 0;
        if (mv == 0ull) {
            if (tid == 0) tsh = -1;
        } else {
            int first = (int)__builtin_ctzll(mv);
            if (tid == first) tsh = ntype[id];
        }
    }
    __syncthreads();
    const int t = tsh;
    if (t < 0) return;

    const int lane = tid & 63;
    const int wv = tid >> 6;
    const int n0 = wv * 32;
    const int m  = lane & 31;
    const int kh = lane >> 5;

    for (int t3 = 0; t3 < 3; ++t3) {
        if (t3 == 2 && !anyq) continue;
        const u16* Bp = Wt + (((size_t)t3 * 8 + t) << 14) + (size_t)(n0 + m) * 128 + kh * 8;
        f32x16 acc0, acc1;
#pragma unroll
        for (int i = 0; i < 16; ++i) { acc0[i] = 0.f; acc1[i] = 0.f; }
#pragma unroll
        for (int kk = 0; kk < 8; ++kk) {
            bf16x8 b  = *(const bf16x8*)(Bp + kk * 16);
            bf16x8 a0 = *(const bf16x8*)&Asm[m][kk * 16 + kh * 8];
            bf16x8 a1 = *(const bf16x8*)&Asm[m + 32][kk * 16 + kh * 8];
            acc0 = __builtin_amdgcn_mfma_f32_32x32x16_bf16(a0, b, acc0, 0, 0, 0);
            acc1 = __builtin_amdgcn_mfma_f32_32x32x16_bf16(a1, b, acc1, 0, 0, 0);
        }
        u16* O = (t3 == 0) ? K : ((t3 == 1) ? V : Q);
#pragma unroll
        for (int r = 0; r < 16; ++r) {
            int row = (r & 3) + 8 * (r >> 2) + 4 * kh;
            int col = n0 + m;
            int g0 = rid[row], g1 = rid[row + 32];
            if (g0 >= 0 && (t3 != 2 || g0 < N_CTR)) O[(size_t)g0 * 128 + col] = f2b(acc0[r]);
            if (g1 >= 0 && (t3 != 2 || g1 < N_CTR)) O[(size_t)g1 * 128 + col] = f2b(acc1[r]);
        }
    }
}

// ------------------------------------------------------------ scores (MFMA)
// Block = 256 edges (8 tiles of 32) x 4 heads (wave = head). A-fragments
// (Ap[h][d][et*32+f], 16 x uint4 = 64 VGPR) are loaded ONCE per wave and
// statically indexed; the tile loop re-uses them for 8 edge-tiles,
// removing the dominant per-tile L2 gather (was 512 line-touches/wave).
// Per tile: coalesced meta, Q 2x16B + K 4x8B gathers, 16 reg-fed MFMAs
// (B gated by et one-hot), per-lane 16-FMA stage-2 dot + shfl_xor(32).
#define STILE 8
__global__ __launch_bounds__(256, 4) void score_mfma_kernel(
    const u16* __restrict__ K, const u16* __restrict__ Q,
    const u16* __restrict__ Ap, const float* __restrict__ relp,
    const int* __restrict__ idx, const int* __restrict__ etype,
    const int* __restrict__ dstid, float* __restrict__ ascore) {
    const int tid = threadIdx.x;
    const int h = tid >> 6, l = tid & 63;
    const int lr = l & 31, kh = l >> 5;
    const int e0 = blockIdx.x * (32 * STILE);    // 3125 blocks * 256 = N_EDGE

    // A-fragments: row d = lr, k = s*16 + kh*8 + j  (static indexing!)
    const u16* ap = Ap + ((h * 32 + lr) << 8) + kh * 8;
    uint4 fa[16];
#pragma unroll
    for (int s = 0; s < 16; ++s) fa[s] = *(const uint4*)(ap + s * 16);

    const float scale = 0.17677669529663687f;    // 1/sqrt(32)

    for (int t = 0; t < STILE; ++t) {
        const int e = e0 + t * 32 + lr;
        const int src = idx[e], dst = dstid[e], et_e = etype[e];

        // Q octets (f = (s&1)*16 + kh*8 + j)
        const u32* qp = (const u32*)(Q + (size_t)dst * 128 + h * 32 + kh * 8);
        u32 q0[4], q1[4];
#pragma unroll
        for (int j = 0; j < 4; ++j) { q0[j] = qp[j]; q1[j] = qp[8 + j]; }

        // K quads for stage 2 (d = (r&3) + 8*(r>>2) + 4*kh)
        const u16* kb = K + (size_t)src * 128 + h * 32 + kh * 4;
        uint2 kv[4];
#pragma unroll
        for (int g = 0; g < 4; ++g) kv[g] = *(const uint2*)(kb + g * 8);

        f32x16 acc;
#pragma unroll
        for (int i = 0; i < 16; ++i) acc[i] = 0.f;

#pragma unroll
        for (int s = 0; s < 16; ++s) {
            union { u32 u[4]; bf16x8 v; } fav, fb;
            fav.u[0] = fa[s].x; fav.u[1] = fa[s].y;
            fav.u[2] = fa[s].z; fav.u[3] = fa[s].w;
            const bool sel = (et_e == (s >> 1));
            const u32* qq = (s & 1) ? q1 : q0;
#pragma unroll
            for (int j = 0; j < 4; ++j) fb.u[j] = sel ? qq[j] : 0u;
            acc = __builtin_amdgcn_mfma_f32_32x32x16_bf16(fav.v, fb.v, acc, 0, 0, 0);
        }

        // stage 2: s_e = sum_d K[e,d] * qw[d,e]
        float partial = 0.f;
#pragma unroll
        for (int g = 0; g < 4; ++g) {
            partial = fmaf(lo16(kv[g].x), acc[g * 4 + 0], partial);
            partial = fmaf(hi16(kv[g].x), acc[g * 4 + 1], partial);
            partial = fmaf(lo16(kv[g].y), acc[g * 4 + 2], partial);
            partial = fmaf(hi16(kv[g].y), acc[g * 4 + 3], partial);
        }
        float ssum = partial + __shfl_xor(partial, 32);
        if (kh == 0) {
            ascore[(size_t)h * N_EDGE + e] = ssum * relp[h * 8 + et_e] * scale;
        }
    }
}

// ------------------------------------------- per-(center,head) softmax pre
// Edge-parallel over centers: m = segment max, inv = 1/segment sum of exp.
__global__ __launch_bounds__(256) void softmax_pre_kernel(
    const float* __restrict__ ascore, const int* __restrict__ ptr,
    float2* __restrict__ mden) {
    int c = blockIdx.x * 256 + threadIdx.x;
    int h = blockIdx.y;
    if (c >= N_CTR) return;
    int e0 = ptr[c], e1 = ptr[c + 1];
    const float* as = ascore + (size_t)h * N_EDGE;
    float m = -3.0e38f;
    for (int e = e0; e < e1; ++e) m = fmaxf(m, as[e]);
    float den = 0.f;
    for (int e = e0; e < e1; ++e) den += __expf(as[e] - m);
    float inv = (den > 0.f) ? 1.f / den : 0.f;
    mden[(size_t)c * 4 + h] = make_float2(m, inv);
}

// ---------------------------------------- aggregate (register one-hot MFMA)
// Block = 16 centers, 4 waves (wave = head h). Per 256-edge chunk: all
// threads stage per-edge metadata {src|bucket<<24, alpha[4] bf16} into a
// tiny LDS table (1 barrier), then each wave runs a barrier-free fragment
// loop over the chunk: per 16 edges build the B fragment by direct u16
// V-gathers (8 independent loads in flight) and 4 one-hot A fragments
// (alpha folded into the selector), 4 MFMA into acc[4] (128 bucket rows x
// 32 cols). Epilogue: buckets -> B16 LDS, then the unchanged Mp-transform.
#define CPB   16
#define CSTR  1032   // u16 per center row of B16 (1024 + 8 pad)
#define CHK   256    // edges staged per chunk
__global__ __launch_bounds__(256, 4) void aggregate_mfma_kernel(
    const u16* __restrict__ V, const u16* __restrict__ Mp,
    const float* __restrict__ ascore, const int* __restrict__ ptr,
    const int* __restrict__ idx, const int* __restrict__ etype,
    const int* __restrict__ dstid, const float2* __restrict__ mden,
    float* __restrict__ out) {
    __shared__ __align__(16) u16 B16[CPB * CSTR];   // 33024 B
    __shared__ u32 meta_sh[CHK];                    // src | bucket<<24
    __shared__ __align__(8) u16 alpha_sh[CHK][4];   // bf16 alpha per head

    const int tid = threadIdx.x;
    const int h = tid >> 6, l = tid & 63;
    const int lr = l & 31, kh = l >> 5;
    const int c0 = blockIdx.x * CPB;
    const int E0 = ptr[c0], E1 = ptr[c0 + CPB];
    const int dcol = h * 32 + lr;                   // this lane's V column

    f32x16 acc[4];
#pragma unroll
    for (int rb = 0; rb < 4; ++rb)
#pragma unroll
        for (int i = 0; i < 16; ++i) acc[rb][i] = 0.f;

    const int nch = (E1 - E0 + CHK - 1) / CHK;
    for (int ch = 0; ch < nch; ++ch) {
        const int eb = E0 + ch * CHK;
        {   // stage metadata + alpha for up to 256 edges (all 256 threads)
            int e = eb + tid;
            u32 mpk = 0xFFu << 24;   // sentinel bucket 255 -> never matches
            u32 a01 = 0u, a23 = 0u;
            if (e < E1) {
                int src = idx[e];
                int bkt = (dstid[e] - c0) * 8 + etype[e];
                mpk = (u32)src | ((u32)bkt << 24);
                const float4* md = (const float4*)(mden + (size_t)dstid[e] * 4);
                float4 mA = md[0], mB = md[1];
                float a0 = __expf(ascore[e] - mA.x) * mA.y;
                float a1 = __expf(ascore[N_EDGE + e] - mA.z) * mA.w;
                float a2 = __expf(ascore[2 * N_EDGE + e] - mB.x) * mB.y;
                float a3 = __expf(ascore[3 * N_EDGE + e] - mB.z) * mB.w;
                a01 = (u32)f2b(a0) | ((u32)f2b(a1) << 16);
                a23 = (u32)f2b(a2) | ((u32)f2b(a3) << 16);
            }
            meta_sh[tid] = mpk;
            *(uint2*)&alpha_sh[tid][0] = make_uint2(a01, a23);
        }
        __syncthreads();

        const int ce = min(CHK, E1 - eb);
        const int cloop = (ce + 15) & ~15;
        for (int s = 0; s < cloop; s += 16) {
            u32 bv[4], fa[4][4];
#pragma unroll
            for (int jj = 0; jj < 4; ++jj) {
                const int e2 = s + kh * 8 + 2 * jj;
                u32 m0 = meta_sh[e2], m1 = meta_sh[e2 + 1];
                u32 al0 = (u32)alpha_sh[e2][h];
                u32 ah1 = (u32)alpha_sh[e2 + 1][h] << 16;
                u32 v0 = (u32)V[(m0 & 0xFFFFFFu) * 128u + (u32)dcol];
                u32 v1 = (u32)V[(m1 & 0xFFFFFFu) * 128u + (u32)dcol];
                bv[jj] = v0 | (v1 << 16);
                int bl0 = (int)(m0 >> 24) - lr;
                int bl1 = (int)(m1 >> 24) - lr;
                fa[0][jj] = (bl0 == 0  ? al0 : 0u) | (bl1 == 0  ? ah1 : 0u);
                fa[1][jj] = (bl0 == 32 ? al0 : 0u) | (bl1 == 32 ? ah1 : 0u);
                fa[2][jj] = (bl0 == 64 ? al0 : 0u) | (bl1 == 64 ? ah1 : 0u);
                fa[3][jj] = (bl0 == 96 ? al0 : 0u) | (bl1 == 96 ? ah1 : 0u);
            }
            union { u32 u[4]; bf16x8 v; } fb;
#pragma unroll
            for (int j = 0; j < 4; ++j) fb.u[j] = bv[j];
#pragma unroll
            for (int rb = 0; rb < 4; ++rb) {
                union { u32 u[4]; bf16x8 v; } fav;
#pragma unroll
                for (int j = 0; j < 4; ++j) fav.u[j] = fa[rb][j];
                acc[rb] = __builtin_amdgcn_mfma_f32_32x32x16_bf16(fav.v, fb.v, acc[rb], 0, 0, 0);
            }
        }
        __syncthreads();   // protect meta/alpha for next chunk
    }

    // buckets -> B16 [center][et*128 + d]
#pragma unroll
    for (int rb = 0; rb < 4; ++rb) {
#pragma unroll
        for (int r = 0; r < 16; ++r) {
            const int g = 32 * rb + (r & 3) + 8 * (r >> 2) + 4 * kh;
            B16[(g >> 3) * CSTR + (g & 7) * 128 + h * 32 + lr] = f2b(acc[rb][r]);
        }
    }
    __syncthreads();

    // MFMA transform: wave h, both f-halves nt = 0,1 (unchanged math)
    const int mrow = l & 15, kq = l >> 4;
#pragma unroll
    for (int nt = 0; nt < 2; ++nt) {
        f32x4 acc2 = {0.f, 0.f, 0.f, 0.f};
        const u16* mp = Mp + h * 8192 + (nt * 16 + mrow) * 256 + kq * 8;
        const u16* ap = B16 + mrow * CSTR + h * 32 + kq * 8;
#pragma unroll
        for (int s = 0; s < 8; ++s) {
            bf16x8 a = *(const bf16x8*)(ap + s * 128);
            bf16x8 b = *(const bf16x8*)(mp + s * 32);
            acc2 = __builtin_amdgcn_mfma_f32_16x16x32_bf16(a, b, acc2, 0, 0, 0);
        }
#pragma unroll
        for (int r = 0; r < 4; ++r) {
            int c = c0 + kq * 4 + r;
            out[(size_t)c * 128 + h * 32 + nt * 16 + mrow] = acc2[r];
        }
    }
}

// ---------------------------------------------------------------- launch
extern "C" void kernel_launch(void* const* d_in, const int* in_sizes, int n_in,
                              void* d_out, int out_size, void* d_ws, size_t ws_size,
                              hipStream_t stream) {
    const float* x     = (const float*)d_in[0];
    const int*   ptr   = (const int*)d_in[1];
    const int*   idx   = (const int*)d_in[2];
    const int*   ntype = (const int*)d_in[3];
    const int*   etype = (const int*)d_in[4];
    const float* k_lin = (const float*)d_in[8];
    const float* q_lin = (const float*)d_in[9];
    const float* v_lin = (const float*)d_in[10];
    const float* a_rel = (const float*)d_in[11];
    const float* m_rel = (const float*)d_in[12];
    const float* relp  = (const float*)d_in[13];
    float* out = (float*)d_out;

    // ws layout (ws_size >= 272 MB established round 2)
    char* ws = (char*)d_ws;
    u16*   Kb    = (u16*)(ws);                  // 51.2 MB
    u16*   Vb    = (u16*)(ws + 51200000);       // 51.2 MB
    u16*   Qb    = (u16*)(ws + 102400000);      // 25.6 MB
    float* As    = (float*)(ws + 128000000);    // 12.8 MB ([4][N_EDGE])
    int*   dstid = (int*)(ws + 140800000);      // 3.2 MB
    u16*   Wt    = (u16*)(ws + 144000000);      // 786,432 B
    int*   meta  = (int*)(ws + 144786432);      // 64 B
    int*   order = (int*)(ws + 144786496);      // 802,816 B
    u16*   Mp    = (u16*)(ws + 145589312);      // 65,536 B
    float2* mden = (float2*)(ws + 145654848);   // 3.2 MB ([N_CTR][4])
    u16*   Apb   = (u16*)(ws + 148854848);      // 65,536 B

    dstfill_kernel<<<391, 256, 0, stream>>>(ptr, dstid);
    fillzero_kernel<<<784, 256, 0, stream>>>(order, meta);
    wprep_kernel<<<24, 256, 0, stream>>>(k_lin, q_lin, v_lin, Wt);
    mprep_kernel<<<128, 256, 0, stream>>>(m_rel, Mp);
    aprep_kernel<<<128, 256, 0, stream>>>(a_rel, Apb);
    hist_kernel<<<782, 256, 0, stream>>>(ntype, meta);
    plan_kernel<<<1, 64, 0, stream>>>(meta);
    scatter_kernel<<<782, 256, 0, stream>>>(ntype, meta, order);
    nl_mfma_kernel<<<NBLK, 256, 0, stream>>>(x, ntype, order, Wt, Kb, Qb, Vb);
    score_mfma_kernel<<<3125, 256, 0, stream>>>(Kb, Qb, Apb, relp, idx, etype, dstid, As);
    softmax_pre_kernel<<<dim3(391, 4), 256, 0, stream>>>(As, ptr, mden);
    aggregate_mfma_kernel<<<6250, 256, 0, stream>>>(Vb, Mp, As, ptr, idx, etype, dstid, mden, out);
}

// Round 7
// 501.856 us; speedup vs baseline: 1.3354x; 1.0060x over previous
//
#include <hip/hip_runtime.h>

typedef unsigned int u32;
typedef unsigned short u16;
typedef __bf16 bf16x8 __attribute__((ext_vector_type(8)));
typedef float f32x4 __attribute__((ext_vector_type(4)));
typedef float f32x16 __attribute__((ext_vector_type(16)));

#define N_SRC 200000
#define N_CTR 100000
#define N_EDGE 800000
#define NBLK 3136  // >= sum_t ceil(cnt_t/64) <= 3133

__device__ __forceinline__ float lo16(u32 u) { return __uint_as_float(u << 16); }
__device__ __forceinline__ float hi16(u32 u) { return __uint_as_float(u & 0xFFFF0000u); }
__device__ __forceinline__ u16 f2b(float f) {
    u32 u = __float_as_uint(f);
    u32 r = (u + 0x7FFFu + ((u >> 16) & 1u)) >> 16;
    return (u16)r;
}

// ---------------------------------------------------------------- dst fill
__global__ __launch_bounds__(256) void dstfill_kernel(const int* __restrict__ ptr,
                                                      int* __restrict__ dst) {
    int c = blockIdx.x * 256 + threadIdx.x;
    if (c < N_CTR) {
        int e1 = ptr[c + 1];
        for (int e = ptr[c]; e < e1; ++e) dst[e] = c;
    }
}

// ---------------------------------------------------- grouping machinery
__global__ __launch_bounds__(256) void fillzero_kernel(int* __restrict__ order,
                                                       int* __restrict__ meta) {
    int i = blockIdx.x * 256 + threadIdx.x;
    if (i < NBLK * 64) order[i] = -1;
    if (blockIdx.x == 0 && threadIdx.x < 16) meta[threadIdx.x] = 0;
}

__global__ __launch_bounds__(256) void hist_kernel(const int* __restrict__ ntype,
                                                   int* __restrict__ meta) {
    __shared__ int lc[8];
    if (threadIdx.x < 8) lc[threadIdx.x] = 0;
    __syncthreads();
    int n = blockIdx.x * 256 + threadIdx.x;
    if (n < N_SRC) atomicAdd(&lc[ntype[n]], 1);
    __syncthreads();
    if (threadIdx.x < 8 && lc[threadIdx.x]) atomicAdd(&meta[threadIdx.x], lc[threadIdx.x]);
}

__global__ void plan_kernel(int* __restrict__ meta) {
    if (threadIdx.x == 0) {
        int total = 0;
        for (int t = 0; t < 8; ++t) {
            meta[8 + t] = total;                 // pos[t] = 64-padded offset
            total += ((meta[t] + 63) >> 6) << 6;
        }
    }
}

__global__ __launch_bounds__(256) void scatter_kernel(const int* __restrict__ ntype,
                                                      int* __restrict__ meta,
                                                      int* __restrict__ order) {
    __shared__ int lc[8], lb[8];
    int tid = threadIdx.x;
    if (tid < 8) lc[tid] = 0;
    __syncthreads();
    int n = blockIdx.x * 256 + tid;
    int t = 0, r = 0;
    bool ok = (n < N_SRC);
    if (ok) { t = ntype[n]; r = atomicAdd(&lc[t], 1); }
    __syncthreads();
    if (tid < 8) lb[tid] = lc[tid] ? atomicAdd(&meta[8 + tid], lc[tid]) : 0;
    __syncthreads();
    if (ok) order[lb[t] + r] = n;
}

// ----------------------------------------------- weight transpose to bf16
__global__ __launch_bounds__(256) void wprep_kernel(const float* __restrict__ Wk,
                                                    const float* __restrict__ Wq,
                                                    const float* __restrict__ Wv,
                                                    u16* __restrict__ Wt) {
    int blk = blockIdx.x;          // t3*8 + t
    int t3 = blk >> 3, t = blk & 7;
    const float* src = ((t3 == 0) ? Wk : ((t3 == 1) ? Wv : Wq)) + ((size_t)t << 14);
    u16* dst = Wt + ((size_t)blk << 14);
    for (int s = threadIdx.x; s < 16384; s += 256) {
        int n = s >> 7, k = s & 127;
        dst[n * 128 + k] = f2b(src[k * 128 + n]);
    }
}

// --------------------------------------- m_rel -> B-fragment layout (bf16)
// m_rel [et][h][d][f] fp32 -> Mp[h][f][et*32+d] bf16  (32768 elems, 64 KB)
__global__ __launch_bounds__(256) void mprep_kernel(const float* __restrict__ m_rel,
                                                    u16* __restrict__ Mp) {
    int i = blockIdx.x * 256 + threadIdx.x;
    int hh = i >> 13, f = (i >> 8) & 31, kk = i & 255;
    int et = kk >> 5, d = kk & 31;
    Mp[i] = f2b(m_rel[(size_t)((et * 4 + hh) * 32 + d) * 32 + f]);
}

// --------------------------------------- a_rel -> A-fragment layout (bf16)
// a_rel [et][h][d][f] fp32 -> Ap[h][d][et*32+f] bf16  (32768 elems, 64 KB)
__global__ __launch_bounds__(256) void aprep_kernel(const float* __restrict__ a_rel,
                                                    u16* __restrict__ Ap) {
    int i = blockIdx.x * 256 + threadIdx.x;
    int h = i >> 13, d = (i >> 8) & 31, et = (i >> 5) & 7, f = i & 31;
    Ap[i] = f2b(a_rel[(size_t)((et * 4 + h) * 32 + d) * 32 + f]);
}

// ------------------------------------------------------- MFMA typed linear
__global__ __launch_bounds__(256) void nl_mfma_kernel(
    const float* __restrict__ x, const int* __restrict__ ntype,
    const int* __restrict__ order, const u16* __restrict__ Wt,
    u16* __restrict__ K, u16* __restrict__ Q, u16* __restrict__ V) {
    __shared__ __align__(16) u16 Asm[64][136];  // row stride 272 B (68 words)
    __shared__ int rid[64];
    __shared__ int tsh, anyq;
    const int tid = threadIdx.x;
    const int r0 = blockIdx.x * 64;

    if (tid < 64) rid[tid] = order[r0 + tid];
    __syncthreads();

    {   // stage A tile as bf16: thread -> (row, 32-col segment).
        // Issued BEFORE the type scan so the x-row gather latency overlaps
        // the single ntype load; one barrier covers both.
        int row = tid >> 2, seg = tid & 3;
        int id = rid[row];
        uint4 w[4];
        if (id >= 0) {
            const float4* xp = (const float4*)(x + (size_t)id * 128 + seg * 32);
#pragma unroll
            for (int q = 0; q < 4; ++q) {
                float4 va = xp[2 * q], vb = xp[2 * q + 1];
                w[q].x = (u32)f2b(va.x) | ((u32)f2b(va.y) << 16);
                w[q].y = (u32)f2b(va.z) | ((u32)f2b(va.w) << 16);
                w[q].z = (u32)f2b(vb.x) | ((u32)f2b(vb.y) << 16);
                w[q].w = (u32)f2b(vb.z) | ((u32)f2b(vb.w) << 16);
            }
        } else {
            uint4 z = {0u, 0u, 0u, 0u};
#pragma unroll
            for (int q = 0; q < 4; ++q) w[q] = z;
        }
        uint4* dst = (uint4*)&Asm[row][seg * 32];
#pragma unroll
        for (int q = 0; q < 4; ++q) dst[q] = w[q];
    }

    // wave-parallel type scan: all valid rows share one type by construction
    // (order is grouped by type, 64-padded) -> ballot + ONE ntype load.
    if (tid < 64) {
        int id = rid[tid];
        unsigned long long mv = __ballot(id >= 0);
        unsigned long long mq = __ballot(id >= 0 && id < N_CTR);
        if (tid == 0) anyq = (mq != 0ull) ? 1 : 0;
        if (mv == 0ull) {
            if (tid == 0) tsh = -1;
        } else {
            int first = (int)__builtin_ctzll(mv);
            if (tid == first) tsh = ntype[id];
        }
    }
    __syncthreads();
    const int t = tsh;
    if (t < 0) return;

    const int lane = tid & 63;
    const int wv = tid >> 6;
    const int n0 = wv * 32;
    const int m  = lane & 31;
    const int kh = lane >> 5;

    for (int t3 = 0; t3 < 3; ++t3) {
        if (t3 == 2 && !anyq) continue;
        const u16* Bp = Wt + (((size_t)t3 * 8 + t) << 14) + (size_t)(n0 + m) * 128 + kh * 8;
        f32x16 acc0, acc1;
#pragma unroll
        for (int i = 0; i < 16; ++i) { acc0[i] = 0.f; acc1[i] = 0.f; }
#pragma unroll
        for (int kk = 0; kk < 8; ++kk) {
            bf16x8 b  = *(const bf16x8*)(Bp + kk * 16);
            bf16x8 a0 = *(const bf16x8*)&Asm[m][kk * 16 + kh * 8];
            bf16x8 a1 = *(const bf16x8*)&Asm[m + 32][kk * 16 + kh * 8];
            acc0 = __builtin_amdgcn_mfma_f32_32x32x16_bf16(a0, b, acc0, 0, 0, 0);
            acc1 = __builtin_amdgcn_mfma_f32_32x32x16_bf16(a1, b, acc1, 0, 0, 0);
        }
        u16* O = (t3 == 0) ? K : ((t3 == 1) ? V : Q);
#pragma unroll
        for (int r = 0; r < 16; ++r) {
            int row = (r & 3) + 8 * (r >> 2) + 4 * kh;
            int col = n0 + m;
            int g0 = rid[row], g1 = rid[row + 32];
            if (g0 >= 0 && (t3 != 2 || g0 < N_CTR)) O[(size_t)g0 * 128 + col] = f2b(acc0[r]);
            if (g1 >= 0 && (t3 != 2 || g1 < N_CTR)) O[(size_t)g1 * 128 + col] = f2b(acc1[r]);
        }
    }
}

// ------------------------------------------------------------ scores (MFMA)
// Block = 256 edges (8 tiles of 32) x 4 heads (wave = head). A-fragments
// (Ap[h][d][et*32+f], 16 x uint4 = 64 VGPR) are loaded ONCE per wave and
// statically indexed; the tile loop re-uses them for 8 edge-tiles.
// Per tile: coalesced meta, Q 2x16B + K 4x8B gathers, 16 reg-fed MFMAs
// (B gated by et one-hot), per-lane 16-FMA stage-2 dot + shfl_xor(32).
#define STILE 8
__global__ __launch_bounds__(256, 4) void score_mfma_kernel(
    const u16* __restrict__ K, const u16* __restrict__ Q,
    const u16* __restrict__ Ap, const float* __restrict__ relp,
    const int* __restrict__ idx, const int* __restrict__ etype,
    const int* __restrict__ dstid, float* __restrict__ ascore) {
    const int tid = threadIdx.x;
    const int h = tid >> 6, l = tid & 63;
    const int lr = l & 31, kh = l >> 5;
    const int e0 = blockIdx.x * (32 * STILE);    // 3125 blocks * 256 = N_EDGE

    // A-fragments: row d = lr, k = s*16 + kh*8 + j  (static indexing!)
    const u16* ap = Ap + ((h * 32 + lr) << 8) + kh * 8;
    uint4 fa[16];
#pragma unroll
    for (int s = 0; s < 16; ++s) fa[s] = *(const uint4*)(ap + s * 16);

    const float scale = 0.17677669529663687f;    // 1/sqrt(32)

    for (int t = 0; t < STILE; ++t) {
        const int e = e0 + t * 32 + lr;
        const int src = idx[e], dst = dstid[e], et_e = etype[e];

        // Q octets (f = (s&1)*16 + kh*8 + j)
        const u32* qp = (const u32*)(Q + (size_t)dst * 128 + h * 32 + kh * 8);
        u32 q0[4], q1[4];
#pragma unroll
        for (int j = 0; j < 4; ++j) { q0[j] = qp[j]; q1[j] = qp[8 + j]; }

        // K quads for stage 2 (d = (r&3) + 8*(r>>2) + 4*kh)
        const u16* kb = K + (size_t)src * 128 + h * 32 + kh * 4;
        uint2 kv[4];
#pragma unroll
        for (int g = 0; g < 4; ++g) kv[g] = *(const uint2*)(kb + g * 8);

        f32x16 acc;
#pragma unroll
        for (int i = 0; i < 16; ++i) acc[i] = 0.f;

#pragma unroll
        for (int s = 0; s < 16; ++s) {
            union { u32 u[4]; bf16x8 v; } fav, fb;
            fav.u[0] = fa[s].x; fav.u[1] = fa[s].y;
            fav.u[2] = fa[s].z; fav.u[3] = fa[s].w;
            const bool sel = (et_e == (s >> 1));
            const u32* qq = (s & 1) ? q1 : q0;
#pragma unroll
            for (int j = 0; j < 4; ++j) fb.u[j] = sel ? qq[j] : 0u;
            acc = __builtin_amdgcn_mfma_f32_32x32x16_bf16(fav.v, fb.v, acc, 0, 0, 0);
        }

        // stage 2: s_e = sum_d K[e,d] * qw[d,e]
        float partial = 0.f;
#pragma unroll
        for (int g = 0; g < 4; ++g) {
            partial = fmaf(lo16(kv[g].x), acc[g * 4 + 0], partial);
            partial = fmaf(hi16(kv[g].x), acc[g * 4 + 1], partial);
            partial = fmaf(lo16(kv[g].y), acc[g * 4 + 2], partial);
            partial = fmaf(hi16(kv[g].y), acc[g * 4 + 3], partial);
        }
        float ssum = partial + __shfl_xor(partial, 32);
        if (kh == 0) {
            ascore[(size_t)h * N_EDGE + e] = ssum * relp[h * 8 + et_e] * scale;
        }
    }
}

// ------------------------- aggregate (fused softmax + register one-hot MFMA)
// Block = 16 centers, 4 waves (wave = head h).
// Pass A: stage scores (4 heads) for the block's edges into LDS; 64 threads
//   (center x head) do the segment max + exp-sum over LDS (online rescale
//   across chunks in the rare multi-chunk case) -> msd_m / msd_i.
//   This replaces the separate softmax_pre kernel + mden round-trip.
// Pass B: stage {voff = src*256, bkt, alpha(4 heads)} per edge (alpha from
//   LDS scores when single-chunk, else global re-read), then the barrier-free
//   per-wave fragment loop: per 16 edges build B by u16 V-gathers and 4
//   one-hot A fragments (alpha folded in), 4 MFMA into acc[4].
// Epilogue: buckets -> B16 (LDS union, barrier-separated), Mp-transform MFMA.
#define CPB   16
#define CSTR  1032   // u16 per center row of B16 (1024 + 8 pad)
#define CHK   256    // edges staged per chunk
struct AggStage {
    float score[4][CHK];   // 4096 B
    u32   voff[CHK];       // 1024 B  (byte offset src*256)
    u16   bkt[CHK];        // 512 B   (cc*8+et, 255 = sentinel)
    u16   alpha[CHK][4];   // 2048 B  (bf16 per head)
    int   pt[CPB + 1];     // 68 B
};
union AggLds {
    AggStage s;
    u16 b16[CPB * CSTR];   // 33024 B
};
__global__ __launch_bounds__(256, 4) void aggregate_mfma_kernel(
    const u16* __restrict__ V, const u16* __restrict__ Mp,
    const float* __restrict__ ascore, const int* __restrict__ ptr,
    const int* __restrict__ idx, const int* __restrict__ etype,
    const int* __restrict__ dstid, float* __restrict__ out) {
    __shared__ __align__(16) AggLds U;
    __shared__ float msd_m[64], msd_i[64];

    const int tid = threadIdx.x;
    const int h = tid >> 6, l = tid & 63;
    const int lr = l & 31, kh = l >> 5;
    const int c0 = blockIdx.x * CPB;

    if (tid <= CPB) U.s.pt[tid] = ptr[c0 + tid];
    __syncthreads();
    const int E0 = U.s.pt[0], E1 = U.s.pt[CPB];
    const int nch = (E1 - E0 + CHK - 1) / CHK;

    // ---------------- pass A: per-(center,head) max + exp-sum ----------------
    float mreg = -3.0e38f, dreg = 0.f;
    const int cc_t = tid >> 2, h_t = tid & 3;       // for tid < 64
    for (int ch = 0; ch < nch; ++ch) {
        const int eb = E0 + ch * CHK;
        const int ce = min(CHK, E1 - eb);
        if (tid < ce) {
            int e = eb + tid;
            U.s.score[0][tid] = ascore[e];
            U.s.score[1][tid] = ascore[N_EDGE + e];
            U.s.score[2][tid] = ascore[2 * N_EDGE + e];
            U.s.score[3][tid] = ascore[3 * N_EDGE + e];
        }
        __syncthreads();
        if (tid < 64) {
            int a = max(U.s.pt[cc_t], eb);
            int b = min(U.s.pt[cc_t + 1], eb + ce);
            if (a < b) {
                float mc = -3.0e38f;
                for (int e = a; e < b; ++e) mc = fmaxf(mc, U.s.score[h_t][e - eb]);
                float mn = fmaxf(mreg, mc);
                float scl = __expf(mreg - mn);   // 0 when mreg was -inf-ish
                float sum = 0.f;
                for (int e = a; e < b; ++e) sum += __expf(U.s.score[h_t][e - eb] - mn);
                dreg = dreg * scl + sum;
                mreg = mn;
            }
        }
        if (ch + 1 < nch) __syncthreads();           // protect score before overwrite
    }
    if (tid < 64) {
        msd_m[tid] = mreg;
        msd_i[tid] = (dreg > 0.f) ? 1.f / dreg : 0.f;
    }
    __syncthreads();

    // ---------------- pass B: alpha staging + one-hot MFMA loop ----------------
    f32x16 acc[4];
#pragma unroll
    for (int rb = 0; rb < 4; ++rb)
#pragma unroll
        for (int i = 0; i < 16; ++i) acc[rb][i] = 0.f;

    const char* Vbase = (const char*)V + (h * 32 + lr) * 2;  // + voff = lane's elem

    for (int ch = 0; ch < nch; ++ch) {
        const int eb = E0 + ch * CHK;
        const int ce = min(CHK, E1 - eb);
        {   // stage voff/bkt/alpha for up to 256 edges (all 256 threads)
            int e = eb + tid;
            u32 vo = 0u; u16 bk = 255; u32 a01 = 0u, a23 = 0u;
            if (tid < ce) {
                int src = idx[e];
                int cc  = dstid[e] - c0;
                bk = (u16)(cc * 8 + etype[e]);
                vo = (u32)src * 256u;
                float s0, s1, s2, s3;
                if (nch == 1) {
                    s0 = U.s.score[0][tid]; s1 = U.s.score[1][tid];
                    s2 = U.s.score[2][tid]; s3 = U.s.score[3][tid];
                } else {
                    s0 = ascore[e];             s1 = ascore[N_EDGE + e];
                    s2 = ascore[2 * N_EDGE + e]; s3 = ascore[3 * N_EDGE + e];
                }
                int b4 = cc * 4;
                float a0 = __expf(s0 - msd_m[b4 + 0]) * msd_i[b4 + 0];
                float a1 = __expf(s1 - msd_m[b4 + 1]) * msd_i[b4 + 1];
                float a2 = __expf(s2 - msd_m[b4 + 2]) * msd_i[b4 + 2];
                float a3 = __expf(s3 - msd_m[b4 + 3]) * msd_i[b4 + 3];
                a01 = (u32)f2b(a0) | ((u32)f2b(a1) << 16);
                a23 = (u32)f2b(a2) | ((u32)f2b(a3) << 16);
            }
            U.s.voff[tid] = vo;
            U.s.bkt[tid]  = bk;
            *(uint2*)&U.s.alpha[tid][0] = make_uint2(a01, a23);
        }
        __syncthreads();

        const int cloop = (ce + 15) & ~15;
        for (int s = 0; s < cloop; s += 16) {
            u32 bv[4], fa[4][4];
#pragma unroll
            for (int jj = 0; jj < 4; ++jj) {
                const int e2 = s + kh * 8 + 2 * jj;
                u32 vo0 = U.s.voff[e2], vo1 = U.s.voff[e2 + 1];
                int bk0 = U.s.bkt[e2],  bk1 = U.s.bkt[e2 + 1];
                u32 al0 = (u32)U.s.alpha[e2][h];
                u32 ah1 = (u32)U.s.alpha[e2 + 1][h] << 16;
                u32 v0 = (u32)*(const u16*)(Vbase + vo0);
                u32 v1 = (u32)*(const u16*)(Vbase + vo1);
                bv[jj] = v0 | (v1 << 16);
                int bl0 = bk0 - lr;
                int bl1 = bk1 - lr;
                fa[0][jj] = (bl0 == 0  ? al0 : 0u) | (bl1 == 0  ? ah1 : 0u);
                fa[1][jj] = (bl0 == 32 ? al0 : 0u) | (bl1 == 32 ? ah1 : 0u);
                fa[2][jj] = (bl0 == 64 ? al0 : 0u) | (bl1 == 64 ? ah1 : 0u);
                fa[3][jj] = (bl0 == 96 ? al0 : 0u) | (bl1 == 96 ? ah1 : 0u);
            }
            union { u32 u[4]; bf16x8 v; } fb;
#pragma unroll
            for (int j = 0; j < 4; ++j) fb.u[j] = bv[j];
#pragma unroll
            for (int rb = 0; rb < 4; ++rb) {
                union { u32 u[4]; bf16x8 v; } fav;
#pragma unroll
                for (int j = 0; j < 4; ++j) fav.u[j] = fa[rb][j];
                acc[rb] = __builtin_amdgcn_mfma_f32_32x32x16_bf16(fav.v, fb.v, acc[rb], 0, 0, 0);
            }
        }
        __syncthreads();   // staging arrays reusable / B16 alias safe
    }

    // buckets -> B16 [center][et*128 + d]  (aliases staging; barrier above)
#pragma unroll
    for (int rb = 0; rb < 4; ++rb) {
#pragma unroll
        for (int r = 0; r < 16; ++r) {
            const int g = 32 * rb + (r & 3) + 8 * (r >> 2) + 4 * kh;
            U.b16[(g >> 3) * CSTR + (g & 7) * 128 + h * 32 + lr] = f2b(acc[rb][r]);
        }
    }
    __syncthreads();

    // MFMA transform: wave h, both f-halves nt = 0,1 (unchanged math)
    const int mrow = l & 15, kq = l >> 4;
#pragma unroll
    for (int nt = 0; nt < 2; ++nt) {
        f32x4 acc2 = {0.f, 0.f, 0.f, 0.f};
        const u16* mp = Mp + h * 8192 + (nt * 16 + mrow) * 256 + kq * 8;
        const u16* ap = U.b16 + mrow * CSTR + h * 32 + kq * 8;
#pragma unroll
        for (int s = 0; s < 8; ++s) {
            bf16x8 a = *(const bf16x8*)(ap + s * 128);
            bf16x8 b = *(const bf16x8*)(mp + s * 32);
            acc2 = __builtin_amdgcn_mfma_f32_16x16x32_bf16(a, b, acc2, 0, 0, 0);
        }
#pragma unroll
        for (int r = 0; r < 4; ++r) {
            int c = c0 + kq * 4 + r;
            out[(size_t)c * 128 + h * 32 + nt * 16 + mrow] = acc2[r];
        }
    }
}

// ---------------------------------------------------------------- launch
extern "C" void kernel_launch(void* const* d_in, const int* in_sizes, int n_in,
                              void* d_out, int out_size, void* d_ws, size_t ws_size,
                              hipStream_t stream) {
    const float* x     = (const float*)d_in[0];
    const int*   ptr   = (const int*)d_in[1];
    const int*   idx   = (const int*)d_in[2];
    const int*   ntype = (const int*)d_in[3];
    const int*   etype = (const int*)d_in[4];
    const float* k_lin = (const float*)d_in[8];
    const float* q_lin = (const float*)d_in[9];
    const float* v_lin = (const float*)d_in[10];
    const float* a_rel = (const float*)d_in[11];
    const float* m_rel = (const float*)d_in[12];
    const float* relp  = (const float*)d_in[13];
    float* out = (float*)d_out;

    // ws layout (ws_size >= 272 MB established round 2)
    char* ws = (char*)d_ws;
    u16*   Kb    = (u16*)(ws);                  // 51.2 MB
    u16*   Vb    = (u16*)(ws + 51200000);       // 51.2 MB
    u16*   Qb    = (u16*)(ws + 102400000);      // 25.6 MB
    float* As    = (float*)(ws + 128000000);    // 12.8 MB ([4][N_EDGE])
    int*   dstid = (int*)(ws + 140800000);      // 3.2 MB
    u16*   Wt    = (u16*)(ws + 144000000);      // 786,432 B
    int*   meta  = (int*)(ws + 144786432);      // 64 B
    int*   order = (int*)(ws + 144786496);      // 802,816 B
    u16*   Mp    = (u16*)(ws + 145589312);      // 65,536 B
    u16*   Apb   = (u16*)(ws + 148854848);      // 65,536 B

    dstfill_kernel<<<391, 256, 0, stream>>>(ptr, dstid);
    fillzero_kernel<<<784, 256, 0, stream>>>(order, meta);
    wprep_kernel<<<24, 256, 0, stream>>>(k_lin, q_lin, v_lin, Wt);
    mprep_kernel<<<128, 256, 0, stream>>>(m_rel, Mp);
    aprep_kernel<<<128, 256, 0, stream>>>(a_rel, Apb);
    hist_kernel<<<782, 256, 0, stream>>>(ntype, meta);
    plan_kernel<<<1, 64, 0, stream>>>(meta);
    scatter_kernel<<<782, 256, 0, stream>>>(ntype, meta, order);
    nl_mfma_kernel<<<NBLK, 256, 0, stream>>>(x, ntype, order, Wt, Kb, Qb, Vb);
    score_mfma_kernel<<<3125, 256, 0, stream>>>(Kb, Qb, Apb, relp, idx, etype, dstid, As);
    aggregate_mfma_kernel<<<6250, 256, 0, stream>>>(Vb, Mp, As, ptr, idx, etype, dstid, out);
}